// Round 9
// baseline (593.678 us; speedup 1.0000x reference)
//
#include <hip/hip_runtime.h>
#include <hip/hip_bf16.h>

typedef __attribute__((ext_vector_type(4))) float f32x4;
typedef __attribute__((ext_vector_type(8))) short s16x8;

#define SEQ 2048
#define DM  2048
#define NH  16
#define HD  128

__device__ __forceinline__ unsigned short f2b(float f){
  unsigned int u = __builtin_bit_cast(unsigned int, f);
  u += 0x7fffu + ((u >> 16) & 1u);
  return (unsigned short)(u >> 16);
}
__device__ __forceinline__ float b2f(unsigned short h){
  unsigned int u = ((unsigned int)h) << 16;
  return __builtin_bit_cast(float, u);
}
__device__ __forceinline__ f32x4 mfma16(s16x8 a, s16x8 b, f32x4 c){
  return __builtin_amdgcn_mfma_f32_16x16x32_bf16(a, b, c, 0, 0, 0);
}

// ---------------------------------------------------------------------------
// One-shot f32 -> bf16 conversion: x -> xb, [wq|wk|wv] -> wfused, wo -> wob.
// ---------------------------------------------------------------------------
__global__ __launch_bounds__(256)
void convert_kernel(const float* __restrict__ x,  const float* __restrict__ wq,
                    const float* __restrict__ wk, const float* __restrict__ wv,
                    const float* __restrict__ wo,
                    unsigned short* __restrict__ xb,
                    unsigned short* __restrict__ wfused,
                    unsigned short* __restrict__ wob)
{
  size_t e = ((size_t)blockIdx.x * 256 + threadIdx.x) * 8;
  const float* src; unsigned short* dst;
  if (e < 16777216){ src = x + e; dst = xb + e; }
  else if (e < 29360128){
    size_t o = e - 16777216;
    int sel = (int)(o >> 22);
    const float* w = sel == 0 ? wq : (sel == 1 ? wk : wv);
    src = w + (o & 4194303); dst = wfused + o;
  } else {
    size_t o = e - 29360128;
    src = wo + o; dst = wob + o;
  }
  float4 a = ((const float4*)src)[0];
  float4 b = ((const float4*)src)[1];
  s16x8 v;
  v[0]=(short)f2b(a.x); v[1]=(short)f2b(a.y); v[2]=(short)f2b(a.z); v[3]=(short)f2b(a.w);
  v[4]=(short)f2b(b.x); v[5]=(short)f2b(b.y); v[6]=(short)f2b(b.z); v[7]=(short)f2b(b.w);
  *(s16x8*)dst = v;
}

// ---------------------------------------------------------------------------
// m201-style 8-phase GEMM: 256x256 tile, BK=64 (32 K-tiles), 8 waves (2Mx4N),
// dbuf-2 x 64KB LDS slots ([A 32K][B 32K], 128B rows, swz ^((row&7)<<4)).
// 4 phases per K-tile, 16 MFMA each (M-quad x ks); B regs reused across the
// quad pair. Stage t+1 spread over t's phases in consumption order
// (Bh0,Bh1,A-firsts,A-tails); counted vmcnt(2) at P1-end (own A-tails) and
// P4-end (next tile's B+A-firsts) + barrier publishes cross-wave.
// L2 policy: XCD x owns fixed nb strip (B-panels L2-resident).
// ---------------------------------------------------------------------------
template<int MODE>
__global__ __launch_bounds__(512, 1)
void gemm8(const unsigned short* __restrict__ A,
           const unsigned short* __restrict__ B,
           unsigned short* __restrict__ qr, unsigned short* __restrict__ kr,
           float* __restrict__ koutf,
           float* __restrict__ voutf, unsigned short* __restrict__ vt,
           float* __restrict__ outf, const int* __restrict__ sp)
{
  extern __shared__ char lds[];
  const int tid  = threadIdx.x;
  const int lane = tid & 63;
  const int w    = tid >> 6;           // 0..7
  const int wr   = w >> 2;             // 0..1  (M half)
  const int wc   = w & 3;              // 0..3  (N quarter)
  const int l15  = lane & 15;
  const int lhi  = lane >> 4;          // 0..3
  const int rq   = lhi << 2;

  // XCD-resident B-strips
  int bid = blockIdx.x;
  int x8 = bid & 7, jb = bid >> 3;
  int mb, nb;
  if (MODE == 0){ nb = 3*x8 + (jb % 3); mb = jb / 3; }
  else          { nb = x8;              mb = jb; }
  const int m0 = mb * 256, n0 = nb * 256;

  const int sp0 = (MODE == 0) ? sp[0] : 0;

  const unsigned short* Abase = A + (size_t)m0 * 2048;
  const unsigned short* Bbase = B + (size_t)n0 * 2048;

  f32x4 acc[8][4] = {};
  s16x8 af[4], af2[4], bf[4];

  // staging source pre-swizzle (lane constants)
  const int rowl0 = w*8 + (lane >> 3);                  // row-local, r2=0
  const int colel = (((lane & 7) ^ ((lane >> 3) & 7)) << 3);
  const int kbsw  = (l15 & 7) << 4;
  const int ldst0 = w*1024 + (lane << 4);

  auto GLOAD = [&](const unsigned short* g, int opoff, int h, int r2, int t, int sl){
    __builtin_amdgcn_global_load_lds(
      (const __attribute__((address_space(1))) void*)
        (g + (size_t)(h*128 + r2*64 + rowl0)*2048 + t*64 + colel),
      (__attribute__((address_space(3))) void*)
        (lds + sl*65536 + opoff + h*16384 + r2*8192 + ldst0),
      16, 0, 0);
  };
  auto LDA4 = [&](int sl, int ks, int f0, s16x8* d){
    const char* base = lds + sl*65536;
    int kb = (ks*64 + lhi*16) ^ kbsw;
    #pragma unroll
    for (int i = 0; i < 4; i++)
      d[i] = *(const s16x8*)(base + (wr*128 + (f0+i)*16 + l15)*128 + kb);
  };
  auto LDB4 = [&](int sl, int ks, s16x8* d){
    const char* base = lds + sl*65536 + 32768;
    int kb = (ks*64 + lhi*16) ^ kbsw;
    #pragma unroll
    for (int j2 = 0; j2 < 4; j2++)
      d[j2] = *(const s16x8*)(base + (wc*64 + j2*16 + l15)*128 + kb);
  };
  auto MM16 = [&](s16x8* a, s16x8* b, int i0){
    __builtin_amdgcn_s_setprio(1);
    #pragma unroll
    for (int i = 0; i < 4; i++)
      #pragma unroll
      for (int j2 = 0; j2 < 4; j2++)
        acc[i0+i][j2] = mfma16(a[i], b[j2], acc[i0+i][j2]);
    __builtin_amdgcn_s_setprio(0);
  };

#define BAR __builtin_amdgcn_s_barrier()
#define VM2 asm volatile("s_waitcnt vmcnt(2)" ::: "memory")
#define VM0 asm volatile("s_waitcnt vmcnt(0)" ::: "memory")

  // ---- prologue: stage tile 0 in consumption order u1..u6 ----
  GLOAD(Bbase,32768,0,0,0,0); GLOAD(Bbase,32768,0,1,0,0);   // u1: B rows 0-127
  GLOAD(Bbase,32768,1,0,0,0); GLOAD(Bbase,32768,1,1,0,0);   // u2: B rows 128-255
  GLOAD(Abase,0,0,0,0,0);     GLOAD(Abase,0,1,0,0,0);       // u3,u4: A firsts
  GLOAD(Abase,0,0,1,0,0);     GLOAD(Abase,0,1,1,0,0);       // u5,u6: A tails
  VM2; BAR;

  #pragma unroll 2
  for (int t = 0; t < 31; t++){
    const int sl = t & 1, ns = sl ^ 1;
    // P1: B[ks0] + A[ks0,M0-3]; stage u1(t+1)
    LDB4(sl,0,bf); LDA4(sl,0,0,af);
    GLOAD(Bbase,32768,0,0,t+1,ns); GLOAD(Bbase,32768,0,1,t+1,ns);
    BAR; MM16(af,bf,0); VM2; BAR;               // own A-tails landed
    // P2: A[ks0,M4-7]; stage u2
    LDA4(sl,0,4,af2);
    GLOAD(Bbase,32768,1,0,t+1,ns); GLOAD(Bbase,32768,1,1,t+1,ns);
    BAR; MM16(af2,bf,4); BAR;
    // P3: B[ks1] + A[ks1,M0-3]; stage u3,u4
    LDB4(sl,1,bf); LDA4(sl,1,0,af);
    GLOAD(Abase,0,0,0,t+1,ns); GLOAD(Abase,0,1,0,t+1,ns);
    BAR; MM16(af,bf,0); BAR;
    // P4: A[ks1,M4-7]; stage u5,u6
    LDA4(sl,1,4,af2);
    GLOAD(Abase,0,0,1,t+1,ns); GLOAD(Abase,0,1,1,t+1,ns);
    BAR; MM16(af2,bf,4); VM2; BAR;              // t+1's B + A-firsts landed
  }
  { // t = 31 (slot 1), no staging
    LDB4(1,0,bf); LDA4(1,0,0,af);
    BAR; MM16(af,bf,0); VM0; BAR;               // drain own A-tails
    LDA4(1,0,4,af2);
    BAR; MM16(af2,bf,4); BAR;
    LDB4(1,1,bf); LDA4(1,1,0,af);
    BAR; MM16(af,bf,0); BAR;
    LDA4(1,1,4,af2);
    MM16(af2,bf,4);
  }
#undef BAR
#undef VM2
#undef VM0

  // ======================= epilogues =======================
  if (MODE == 1){
    #pragma unroll
    for (int i = 0; i < 8; i++)
      #pragma unroll
      for (int r = 0; r < 4; r++){
        int m = m0 + wr*128 + i*16 + rq + r;
        #pragma unroll
        for (int j2 = 0; j2 < 4; j2++)
          outf[(size_t)m*DM + n0 + wc*64 + j2*16 + l15] = acc[i][j2][r];
      }
    return;
  }

  const int b  = m0 >> 11;
  const int s0 = m0 & 2047;

  if (nb < 16){
    // ---- RoPE Q/K epilogue with block-local LDS angle tables ----
    const bool isK = (nb >= 8);
    unsigned short* dqk = isK ? kr : qr;
    const int fbase = (nb & 7) * 128;
    const int odd = lane & 1;

    __syncthreads();   // all K-loop LDS reads done; reuse LDS for tables
    float2* T2 = (float2*)lds;             // [32 s_lo][128 f]
    float2* T1 = (float2*)(lds + 32768);   // [ 8 s_hi][128 f]
    for (int idx = tid; idx < 5120; idx += 512){
      int fl = idx & 127;
      float th = exp2f(-(float)(fbase + fl) * (13.287712379549449f / 1024.0f));
      float sn, cn;
      if (idx < 4096){
        __sincosf((float)(idx >> 7) * th, &sn, &cn);
        T2[idx] = make_float2(cn, sn);
      } else {
        int sh = (idx - 4096) >> 7;
        __sincosf((float)(sp0 + s0 + sh*32) * th, &sn, &cn);
        T1[idx - 4096] = make_float2(cn, sn);
      }
    }
    __syncthreads();

    #pragma unroll
    for (int i = 0; i < 8; i++){
      #pragma unroll
      for (int r = 0; r < 4; r++){
        int srow = wr*128 + i*16 + rq + r;
        int s  = s0 + srow;
        int sh = srow >> 5, sl2 = srow & 31;
        #pragma unroll
        for (int j2 = 0; j2 < 4; j2++){
          float v  = acc[i][j2][r];
          float vx = __shfl_xor(v, 1);
          int nn_loc = wc*64 + j2*16 + l15;
          int fl = nn_loc >> 1;
          float2 a1 = T1[sh*128 + fl];
          float2 a2 = T2[sl2*128 + fl];
          float cn = a1.x*a2.x - a1.y*a2.y;
          float sn = a1.y*a2.x + a1.x*a2.y;
          float x1 = odd ? vx : v;
          float x2 = odd ? v  : vx;
          float ov = odd ? (x1*sn + x2*cn) : (x1*cn - x2*sn);
          int c = fbase + fl + (odd ? 1024 : 0);
          size_t adr = ((size_t)(b*NH + (c >> 7))*SEQ + s)*HD + (c & 127);
          dqk[adr] = f2b(ov);
          if (isK) koutf[adr] = ov;
        }
      }
    }
  } else {
    // ---- V epilogue: vout f32 (B,H,S,hd) + vt bf16 (B,H,hd,S) ----
    #pragma unroll
    for (int i = 0; i < 8; i++){
      int sb = s0 + wr*128 + i*16 + rq;
      #pragma unroll
      for (int j2 = 0; j2 < 4; j2++){
        int d = (nb - 16)*256 + wc*64 + j2*16 + l15;
        int h = d >> 7, dd = d & 127;
        size_t vb = ((size_t)(b*NH + h)*SEQ + sb)*HD + dd;
        #pragma unroll
        for (int r = 0; r < 4; r++)
          voutf[vb + (size_t)r*HD] = acc[i][j2][r];
        ushort4 pk;
        pk.x = f2b(acc[i][j2][0]); pk.y = f2b(acc[i][j2][1]);
        pk.z = f2b(acc[i][j2][2]); pk.w = f2b(acc[i][j2][3]);
        *(ushort4*)(vt + ((size_t)(b*NH + h)*HD + dd)*SEQ + sb) = pk;
      }
    }
  }
}

// ---------------------------------------------------------------------------
// Causal flash attention v4: 4 waves x 16 q-rows, KVBLK=64. Paired q-tiles
// for uniform load. K 64x256B XOR-swz; V^T / P at 144B pitch. Row-sum via
// ones-MFMA; defer-max (THR=8).
// ---------------------------------------------------------------------------
__global__ __launch_bounds__(256)
void attn_kernel(const unsigned short* __restrict__ qr,
                 const unsigned short* __restrict__ kr,
                 const unsigned short* __restrict__ vt,
                 unsigned short* __restrict__ attnout)
{
  const int pair = blockIdx.x;          // 0..15
  const int bh   = blockIdx.y;          // 0..63
  const int tid  = threadIdx.x;
  const int lane = tid & 63;
  const int w    = tid >> 6;

  __shared__ __align__(16) char Klds[64 * 256];    // 16KB
  __shared__ __align__(16) char Vlds[128 * 144];   // 18KB
  __shared__ __align__(16) char Plds[4][16 * 144]; // 9KB

  const int l15 = lane & 15;
  const int lhi = lane >> 4;
  const int rq  = lhi << 2;
  char* pw = &Plds[w][0];

  s16x8 ones;
  #pragma unroll
  for (int i = 0; i < 8; i++) ones[i] = (short)0x3F80;

  const int b = bh >> 4, h = bh & 15;

  for (int ph = 0; ph < 2; ph++){
    const int qtile = ph ? (31 - pair) : pair;
    const int q0w = qtile*64 + w*16;

    s16x8 qf[4];
    const unsigned short* qbase = qr + ((size_t)bh*SEQ + q0w + l15) * HD + lhi*8;
    #pragma unroll
    for (int c = 0; c < 4; c++) qf[c] = *(const s16x8*)(qbase + c*32);

    f32x4 o[8] = {};
    f32x4 osum = {};
    float mrow[4] = {-1e30f,-1e30f,-1e30f,-1e30f};

    const int ntiles = qtile + 1;
    for (int t = 0; t < ntiles; t++){
      const int kv0 = t * 64;
      __syncthreads();
      { // stage K tile (64 x 128 bf16, rows 256B, XOR swz (r&15)<<4)
        int r = tid >> 2, q4 = tid & 3;
        const unsigned short* src = kr + ((size_t)bh*SEQ + kv0 + r) * HD + q4*32;
        int sw = (r & 15) << 4;
        char* drow = Klds + r*256;
        #pragma unroll
        for (int k = 0; k < 4; k++)
          *(s16x8*)(drow + ((q4*64 + k*16) ^ sw)) = *(const s16x8*)(src + k*8);
      }
      { // stage V^T tile (128 d-rows x 64 kv, 144B pitch)
        int r = tid >> 1, h2 = tid & 1;
        const unsigned short* src = vt + ((size_t)bh*HD + r) * SEQ + kv0 + h2*32;
        char* drow = Vlds + r*144 + h2*64;
        #pragma unroll
        for (int k = 0; k < 4; k++)
          *(s16x8*)(drow + k*16) = *(const s16x8*)(src + k*8);
      }
      __syncthreads();

      // ---- S = Q K^T (16 q x 64 kv as four 16x16 tiles) ----
      f32x4 st[4];
      #pragma unroll
      for (int j = 0; j < 4; j++) st[j] = (f32x4){0.f,0.f,0.f,0.f};
      #pragma unroll
      for (int j = 0; j < 4; j++){
        int krw = j*16 + l15;
        int sw  = (krw & 15) << 4;
        #pragma unroll
        for (int c = 0; c < 4; c++){
          s16x8 kf = *(const s16x8*)(Klds + krw*256 + ((c*64 + lhi*16) ^ sw));
          st[j] = mfma16(qf[c], kf, st[j]);
        }
      }

      const float sc = 0.08838834764831845f;
      #pragma unroll
      for (int j = 0; j < 4; j++)
        #pragma unroll
        for (int r = 0; r < 4; r++){
          int qrow = q0w + rq + r;
          int kvc  = kv0 + j*16 + l15;
          st[j][r] = (kvc > qrow) ? -1e30f : st[j][r] * sc;
        }

      float mt[4];
      #pragma unroll
      for (int r = 0; r < 4; r++)
        mt[r] = fmaxf(fmaxf(st[0][r], st[1][r]), fmaxf(st[2][r], st[3][r]));
      #pragma unroll
      for (int mk = 1; mk < 16; mk <<= 1)
        #pragma unroll
        for (int r = 0; r < 4; r++) mt[r] = fmaxf(mt[r], __shfl_xor(mt[r], mk));

      int ok = 1;
      #pragma unroll
      for (int r = 0; r < 4; r++) ok &= (mt[r] <= mrow[r] + 8.0f) ? 1 : 0;
      if (!__all(ok)){
        float al[4];
        #pragma unroll
        for (int r = 0; r < 4; r++){
          float mn = fmaxf(mrow[r], mt[r]);
          al[r] = __expf(mrow[r] - mn);
          mrow[r] = mn;
        }
        #pragma unroll
        for (int c = 0; c < 8; c++)
          #pragma unroll
          for (int r = 0; r < 4; r++) o[c][r] *= al[r];
        #pragma unroll
        for (int r = 0; r < 4; r++) osum[r] *= al[r];
      }

      // ---- P = exp(S - m) -> per-wave LDS (144B pitch) ----
      #pragma unroll
      for (int r = 0; r < 4; r++){
        char* prb = pw + (rq + r)*144;
        #pragma unroll
        for (int j = 0; j < 4; j++){
          float p = __expf(st[j][r] - mrow[r]);
          *(unsigned short*)(prb + (j*16 + l15)*2) = f2b(p);
        }
      }

      asm volatile("s_waitcnt lgkmcnt(0)" ::: "memory");

      // ---- O += P V (two K=32 passes) ----
      #pragma unroll
      for (int ks = 0; ks < 2; ks++){
        s16x8 pa = *(const s16x8*)(pw + l15*144 + ks*64 + lhi*16);
        #pragma unroll
        for (int c = 0; c < 8; c++){
          int d = c*16 + l15;
          s16x8 vf = *(const s16x8*)(Vlds + d*144 + ks*64 + lhi*16);
          o[c] = mfma16(pa, vf, o[c]);
        }
        osum = mfma16(pa, ones, osum);
      }
    }

    #pragma unroll
    for (int r = 0; r < 4; r++){
      float inv = 1.0f / osum[r];
      int s2 = q0w + rq + r;
      size_t base = ((size_t)(b*SEQ + s2)) * DM + h*HD;
      #pragma unroll
      for (int c = 0; c < 8; c++)
        attnout[base + c*16 + l15] = f2b(o[c][r] * inv);
    }
  }
}

// ---------------------------------------------------------------------------
extern "C" void kernel_launch(void* const* d_in, const int* in_sizes, int n_in,
                              void* d_out, int out_size, void* d_ws, size_t ws_size,
                              hipStream_t stream)
{
  const float* x  = (const float*)d_in[0];
  const float* wq = (const float*)d_in[1];
  const float* wk = (const float*)d_in[2];
  const float* wv = (const float*)d_in[3];
  const float* wo = (const float*)d_in[4];
  const int*   sp = (const int*)d_in[5];

  float* out  = (float*)d_out;            // (B,S,D) f32
  float* kout = out + 16777216;           // (B,H,S,hd) f32
  float* vout = out + 33554432;           // (B,H,S,hd) f32

  char* ws = (char*)d_ws;
  unsigned short* xb      = (unsigned short*)ws;                  // 8192x2048 bf16
  unsigned short* wfused  = (unsigned short*)(ws + 33554432);     // 6144x2048 bf16
  unsigned short* wob     = (unsigned short*)(ws + 58720256);     // 2048x2048 bf16
  unsigned short* qr      = (unsigned short*)(ws + 67108864);     // (B,H,S,hd) bf16
  unsigned short* kr      = (unsigned short*)(ws + 100663296);    // (B,H,S,hd) bf16
  unsigned short* vt      = (unsigned short*)(ws + 134217728);    // (B,H,hd,S) bf16
  unsigned short* attnout = (unsigned short*)ws;                  // alias xb

  hipFuncSetAttribute((const void*)gemm8<0>,
                      hipFuncAttributeMaxDynamicSharedMemorySize, 131072);
  hipFuncSetAttribute((const void*)gemm8<1>,
                      hipFuncAttributeMaxDynamicSharedMemorySize, 131072);

  // 1) f32 -> bf16 conversion
  convert_kernel<<<16384, 256, 0, stream>>>(x, wq, wk, wv, wo, xb, wfused, wob);
  // 2) fused QKV GEMM (8-phase 256^2) with RoPE/V epilogues
  gemm8<0><<<768, 512, 131072, stream>>>(xb, wfused, qr, kr, kout,
                                         vout, vt, nullptr, sp);
  // 3) causal flash attention (KVBLK=64, paired q-tiles)
  attn_kernel<<<dim3(16, 64), 256, 0, stream>>>(qr, kr, vt, attnout);
  // 4) output GEMM (8-phase 256^2)
  gemm8<1><<<256, 512, 131072, stream>>>(attnout, wob, nullptr, nullptr,
                                         nullptr, nullptr, nullptr, out, nullptr);
}

// Round 10
// 586.248 us; speedup vs baseline: 1.0127x; 1.0127x over previous
//
#include <hip/hip_runtime.h>
#include <hip/hip_bf16.h>

typedef __attribute__((ext_vector_type(4))) float f32x4;
typedef __attribute__((ext_vector_type(8))) short s16x8;

#define SEQ 2048
#define DM  2048
#define NH  16
#define HD  128

__device__ __forceinline__ unsigned short f2b(float f){
  unsigned int u = __builtin_bit_cast(unsigned int, f);
  u += 0x7fffu + ((u >> 16) & 1u);
  return (unsigned short)(u >> 16);
}
__device__ __forceinline__ float b2f(unsigned short h){
  unsigned int u = ((unsigned int)h) << 16;
  return __builtin_bit_cast(float, u);
}
__device__ __forceinline__ f32x4 mfma16(s16x8 a, s16x8 b, f32x4 c){
  return __builtin_amdgcn_mfma_f32_16x16x32_bf16(a, b, c, 0, 0, 0);
}

// ---------------------------------------------------------------------------
// One-shot f32 -> bf16 conversion: x -> xb, [wq|wk|wv] -> wfused, wo -> wob.
// ---------------------------------------------------------------------------
__global__ __launch_bounds__(256)
void convert_kernel(const float* __restrict__ x,  const float* __restrict__ wq,
                    const float* __restrict__ wk, const float* __restrict__ wv,
                    const float* __restrict__ wo,
                    unsigned short* __restrict__ xb,
                    unsigned short* __restrict__ wfused,
                    unsigned short* __restrict__ wob)
{
  size_t e = ((size_t)blockIdx.x * 256 + threadIdx.x) * 8;
  const float* src; unsigned short* dst;
  if (e < 16777216){ src = x + e; dst = xb + e; }
  else if (e < 29360128){
    size_t o = e - 16777216;
    int sel = (int)(o >> 22);
    const float* w = sel == 0 ? wq : (sel == 1 ? wk : wv);
    src = w + (o & 4194303); dst = wfused + o;
  } else {
    size_t o = e - 29360128;
    src = wo + o; dst = wob + o;
  }
  float4 a = ((const float4*)src)[0];
  float4 b = ((const float4*)src)[1];
  s16x8 v;
  v[0]=(short)f2b(a.x); v[1]=(short)f2b(a.y); v[2]=(short)f2b(a.z); v[3]=(short)f2b(a.w);
  v[4]=(short)f2b(b.x); v[5]=(short)f2b(b.y); v[6]=(short)f2b(b.z); v[7]=(short)f2b(b.w);
  *(s16x8*)dst = v;
}

// ---------------------------------------------------------------------------
// m97-structure GEMM + conflict-free swizzle: 128x128 tile, BK=64, 4 waves,
// single-buffered 32KB LDS, 2 barriers/K-tile (__syncthreads drains vmcnt).
// LDS rows 128B; involutive XOR swizzle ^((row&7)<<4): global_load_lds writes
// linear dest with pre-swizzled source granule ((lane&7)^rr), ds_reads XOR
// the column. 3-4 blocks/CU co-resident -> wave-level MFMA/LDS overlap.
// L2 policy: XCD x owns fixed nb strip (B-panels L2-resident).
// MODE 0: A=xb, B=wfused (48 nb: 0-15 Q rope, 16-31 K rope+f32, 32-47 V).
// MODE 1: A=attnout, B=wob -> outf f32 (16 nb).
// ---------------------------------------------------------------------------
template<int MODE>
__global__ __launch_bounds__(256)
void gemm97(const unsigned short* __restrict__ A,
            const unsigned short* __restrict__ B,
            unsigned short* __restrict__ qr, unsigned short* __restrict__ kr,
            float* __restrict__ koutf,
            float* __restrict__ voutf, unsigned short* __restrict__ vt,
            float* __restrict__ outf, const int* __restrict__ sp)
{
  __shared__ __align__(16) char smem[32768];     // A 16K | B 16K
  char* Alds = smem;
  char* Blds = smem + 16384;

  const int tid  = threadIdx.x;
  const int lane = tid & 63;
  const int w    = tid >> 6;
  const int wr   = w >> 1, wc = w & 1;
  const int l15  = lane & 15;
  const int lhi  = lane >> 4;
  const int rq   = lhi << 2;

  // XCD-resident B strips
  int bid = blockIdx.x;
  int x8 = bid & 7, jb = bid >> 3;
  int mb, nb;
  if (MODE == 0){ nb = 6*x8 + (jb % 6); mb = jb / 6; }
  else          { nb = 2*x8 + (jb & 1); mb = jb >> 1; }
  const int m0 = mb * 128, n0 = nb * 128;

  const int sp0 = (MODE == 0) ? sp[0] : 0;

  const unsigned short* Abase = A + (size_t)m0 * 2048;
  const unsigned short* Bbase = B + (size_t)n0 * 2048;

  f32x4 acc[4][4] = {};

  const int rr  = lane >> 3;                        // 0..7 (row within 8)
  const int cel = ((lane & 7) ^ rr) << 3;           // pre-swizzled col (elements)

  for (int k0 = 0; k0 < 2048; k0 += 64){
    __syncthreads();
    #pragma unroll
    for (int q = 0; q < 4; q++){
      int row = q*32 + w*8 + rr;
      __builtin_amdgcn_global_load_lds(
        (const __attribute__((address_space(1))) void*)(Abase + (size_t)row*2048 + k0 + cel),
        (__attribute__((address_space(3))) void*)(Alds + q*4096 + w*1024),
        16, 0, 0);
      __builtin_amdgcn_global_load_lds(
        (const __attribute__((address_space(1))) void*)(Bbase + (size_t)row*2048 + k0 + cel),
        (__attribute__((address_space(3))) void*)(Blds + q*4096 + w*1024),
        16, 0, 0);
    }
    __syncthreads();
    #pragma unroll
    for (int ks = 0; ks < 2; ks++){
      const int kb = ks*64 + lhi*16;
      const int sw = (l15 & 7) << 4;
      s16x8 af[4], bfr[4];
      #pragma unroll
      for (int i = 0; i < 4; i++){
        int row = wr*64 + i*16 + l15;
        af[i] = *(const s16x8*)(Alds + row*128 + (kb ^ sw));
      }
      #pragma unroll
      for (int j = 0; j < 4; j++){
        int row = wc*64 + j*16 + l15;
        bfr[j] = *(const s16x8*)(Blds + row*128 + (kb ^ sw));
      }
      #pragma unroll
      for (int i = 0; i < 4; i++)
        #pragma unroll
        for (int j = 0; j < 4; j++)
          acc[i][j] = mfma16(af[i], bfr[j], acc[i][j]);
    }
  }

  // ======================= epilogues =======================
  const int col = l15;

  if (MODE == 1){
    #pragma unroll
    for (int i = 0; i < 4; i++)
      #pragma unroll
      for (int j = 0; j < 4; j++)
        #pragma unroll
        for (int r = 0; r < 4; r++)
          outf[(size_t)(m0 + wr*64 + i*16 + rq + r) * DM + n0 + wc*64 + j*16 + col]
            = acc[i][j][r];
    return;
  }

  const int b  = m0 >> 11;
  const int s0 = m0 & 2047;

  if (nb < 32){
    // ---- RoPE Q/K epilogue, block-local LDS angle tables ----
    const bool isK = (nb >= 16);
    unsigned short* dqk = isK ? kr : qr;
    const int fbase = (nb & 15) * 64;
    const int odd = lane & 1;

    __syncthreads();   // all waves done reading A/B; reuse LDS
    float2* T2 = (float2*)Alds;          // [32 s_lo][64 f]
    float2* T1 = (float2*)Blds;          // [ 4 s_hi][64 f]
    for (int idx = tid; idx < 2304; idx += 256){
      int fl = idx & 63;
      float th = exp2f(-(float)(fbase + fl) * (13.287712379549449f / 1024.0f));
      float sn, cn;
      if (idx < 2048){
        __sincosf((float)(idx >> 6) * th, &sn, &cn);
        T2[idx] = make_float2(cn, sn);
      } else {
        int sh = (idx - 2048) >> 6;
        __sincosf((float)(sp0 + s0 + sh*32) * th, &sn, &cn);
        T1[idx - 2048] = make_float2(cn, sn);
      }
    }
    __syncthreads();

    #pragma unroll
    for (int i = 0; i < 4; i++){
      #pragma unroll
      for (int r = 0; r < 4; r++){
        int srow = wr*64 + i*16 + rq + r;
        int s  = s0 + srow;
        int sh = srow >> 5, sl = srow & 31;
        #pragma unroll
        for (int j = 0; j < 4; j++){
          float v  = acc[i][j][r];
          float vx = __shfl_xor(v, 1);
          int nn_loc = wc*64 + j*16 + col;
          int fl = nn_loc >> 1;
          float2 a1 = T1[sh*64 + fl];
          float2 a2 = T2[sl*64 + fl];
          float cn = a1.x*a2.x - a1.y*a2.y;
          float sn = a1.y*a2.x + a1.x*a2.y;
          float x1 = odd ? vx : v;
          float x2 = odd ? v  : vx;
          float ov = odd ? (x1*sn + x2*cn) : (x1*cn - x2*sn);
          int c = fbase + fl + (odd ? 1024 : 0);
          size_t adr = ((size_t)(b*NH + (c >> 7))*SEQ + s)*HD + (c & 127);
          dqk[adr] = f2b(ov);
          if (isK) koutf[adr] = ov;
        }
      }
    }
  } else {
    // ---- V epilogue: vout f32 (B,H,S,hd) + vt bf16 (B,H,hd,S) ----
    #pragma unroll
    for (int i = 0; i < 4; i++){
      int sb = s0 + wr*64 + i*16 + rq;
      #pragma unroll
      for (int j = 0; j < 4; j++){
        int d = (nb - 32)*128 + wc*64 + j*16 + col;
        int h = d >> 7, dd = d & 127;
        size_t vb = ((size_t)(b*NH + h)*SEQ + sb)*HD + dd;
        #pragma unroll
        for (int r = 0; r < 4; r++)
          voutf[vb + (size_t)r*HD] = acc[i][j][r];
        ushort4 pk;
        pk.x = f2b(acc[i][j][0]); pk.y = f2b(acc[i][j][1]);
        pk.z = f2b(acc[i][j][2]); pk.w = f2b(acc[i][j][3]);
        *(ushort4*)(vt + ((size_t)(b*NH + h)*HD + dd)*SEQ + sb) = pk;
      }
    }
  }
}

// ---------------------------------------------------------------------------
// Causal flash attention v4: 4 waves x 16 q-rows, KVBLK=64. Paired q-tiles
// for uniform load. K 64x256B XOR-swz; V^T / P at 144B pitch. Row-sum via
// ones-MFMA; defer-max (THR=8).
// ---------------------------------------------------------------------------
__global__ __launch_bounds__(256)
void attn_kernel(const unsigned short* __restrict__ qr,
                 const unsigned short* __restrict__ kr,
                 const unsigned short* __restrict__ vt,
                 unsigned short* __restrict__ attnout)
{
  const int pair = blockIdx.x;          // 0..15
  const int bh   = blockIdx.y;          // 0..63
  const int tid  = threadIdx.x;
  const int lane = tid & 63;
  const int w    = tid >> 6;

  __shared__ __align__(16) char Klds[64 * 256];    // 16KB
  __shared__ __align__(16) char Vlds[128 * 144];   // 18KB
  __shared__ __align__(16) char Plds[4][16 * 144]; // 9KB

  const int l15 = lane & 15;
  const int lhi = lane >> 4;
  const int rq  = lhi << 2;
  char* pw = &Plds[w][0];

  s16x8 ones;
  #pragma unroll
  for (int i = 0; i < 8; i++) ones[i] = (short)0x3F80;

  const int b = bh >> 4, h = bh & 15;

  for (int ph = 0; ph < 2; ph++){
    const int qtile = ph ? (31 - pair) : pair;
    const int q0w = qtile*64 + w*16;

    s16x8 qf[4];
    const unsigned short* qbase = qr + ((size_t)bh*SEQ + q0w + l15) * HD + lhi*8;
    #pragma unroll
    for (int c = 0; c < 4; c++) qf[c] = *(const s16x8*)(qbase + c*32);

    f32x4 o[8] = {};
    f32x4 osum = {};
    float mrow[4] = {-1e30f,-1e30f,-1e30f,-1e30f};

    const int ntiles = qtile + 1;
    for (int t = 0; t < ntiles; t++){
      const int kv0 = t * 64;
      __syncthreads();
      { // stage K tile (64 x 128 bf16, rows 256B, XOR swz (r&15)<<4)
        int r = tid >> 2, q4 = tid & 3;
        const unsigned short* src = kr + ((size_t)bh*SEQ + kv0 + r) * HD + q4*32;
        int sw = (r & 15) << 4;
        char* drow = Klds + r*256;
        #pragma unroll
        for (int k = 0; k < 4; k++)
          *(s16x8*)(drow + ((q4*64 + k*16) ^ sw)) = *(const s16x8*)(src + k*8);
      }
      { // stage V^T tile (128 d-rows x 64 kv, 144B pitch)
        int r = tid >> 1, h2 = tid & 1;
        const unsigned short* src = vt + ((size_t)bh*HD + r) * SEQ + kv0 + h2*32;
        char* drow = Vlds + r*144 + h2*64;
        #pragma unroll
        for (int k = 0; k < 4; k++)
          *(s16x8*)(drow + k*16) = *(const s16x8*)(src + k*8);
      }
      __syncthreads();

      // ---- S = Q K^T (16 q x 64 kv as four 16x16 tiles) ----
      f32x4 st[4];
      #pragma unroll
      for (int j = 0; j < 4; j++) st[j] = (f32x4){0.f,0.f,0.f,0.f};
      #pragma unroll
      for (int j = 0; j < 4; j++){
        int krw = j*16 + l15;
        int sw  = (krw & 15) << 4;
        #pragma unroll
        for (int c = 0; c < 4; c++){
          s16x8 kf = *(const s16x8*)(Klds + krw*256 + ((c*64 + lhi*16) ^ sw));
          st[j] = mfma16(qf[c], kf, st[j]);
        }
      }

      const float sc = 0.08838834764831845f;
      #pragma unroll
      for (int j = 0; j < 4; j++)
        #pragma unroll
        for (int r = 0; r < 4; r++){
          int qrow = q0w + rq + r;
          int kvc  = kv0 + j*16 + l15;
          st[j][r] = (kvc > qrow) ? -1e30f : st[j][r] * sc;
        }

      float mt[4];
      #pragma unroll
      for (int r = 0; r < 4; r++)
        mt[r] = fmaxf(fmaxf(st[0][r], st[1][r]), fmaxf(st[2][r], st[3][r]));
      #pragma unroll
      for (int mk = 1; mk < 16; mk <<= 1)
        #pragma unroll
        for (int r = 0; r < 4; r++) mt[r] = fmaxf(mt[r], __shfl_xor(mt[r], mk));

      int ok = 1;
      #pragma unroll
      for (int r = 0; r < 4; r++) ok &= (mt[r] <= mrow[r] + 8.0f) ? 1 : 0;
      if (!__all(ok)){
        float al[4];
        #pragma unroll
        for (int r = 0; r < 4; r++){
          float mn = fmaxf(mrow[r], mt[r]);
          al[r] = __expf(mrow[r] - mn);
          mrow[r] = mn;
        }
        #pragma unroll
        for (int c = 0; c < 8; c++)
          #pragma unroll
          for (int r = 0; r < 4; r++) o[c][r] *= al[r];
        #pragma unroll
        for (int r = 0; r < 4; r++) osum[r] *= al[r];
      }

      // ---- P = exp(S - m) -> per-wave LDS (144B pitch) ----
      #pragma unroll
      for (int r = 0; r < 4; r++){
        char* prb = pw + (rq + r)*144;
        #pragma unroll
        for (int j = 0; j < 4; j++){
          float p = __expf(st[j][r] - mrow[r]);
          *(unsigned short*)(prb + (j*16 + l15)*2) = f2b(p);
        }
      }

      asm volatile("s_waitcnt lgkmcnt(0)" ::: "memory");

      // ---- O += P V (two K=32 passes) ----
      #pragma unroll
      for (int ks = 0; ks < 2; ks++){
        s16x8 pa = *(const s16x8*)(pw + l15*144 + ks*64 + lhi*16);
        #pragma unroll
        for (int c = 0; c < 8; c++){
          int d = c*16 + l15;
          s16x8 vf = *(const s16x8*)(Vlds + d*144 + ks*64 + lhi*16);
          o[c] = mfma16(pa, vf, o[c]);
        }
        osum = mfma16(pa, ones, osum);
      }
    }

    #pragma unroll
    for (int r = 0; r < 4; r++){
      float inv = 1.0f / osum[r];
      int s2 = q0w + rq + r;
      size_t base = ((size_t)(b*SEQ + s2)) * DM + h*HD;
      #pragma unroll
      for (int c = 0; c < 8; c++)
        attnout[base + c*16 + l15] = f2b(o[c][r] * inv);
    }
  }
}

// ---------------------------------------------------------------------------
extern "C" void kernel_launch(void* const* d_in, const int* in_sizes, int n_in,
                              void* d_out, int out_size, void* d_ws, size_t ws_size,
                              hipStream_t stream)
{
  const float* x  = (const float*)d_in[0];
  const float* wq = (const float*)d_in[1];
  const float* wk = (const float*)d_in[2];
  const float* wv = (const float*)d_in[3];
  const float* wo = (const float*)d_in[4];
  const int*   sp = (const int*)d_in[5];

  float* out  = (float*)d_out;            // (B,S,D) f32
  float* kout = out + 16777216;           // (B,H,S,hd) f32
  float* vout = out + 33554432;           // (B,H,S,hd) f32

  char* ws = (char*)d_ws;
  unsigned short* xb      = (unsigned short*)ws;                  // 8192x2048 bf16
  unsigned short* wfused  = (unsigned short*)(ws + 33554432);     // 6144x2048 bf16
  unsigned short* wob     = (unsigned short*)(ws + 58720256);     // 2048x2048 bf16
  unsigned short* qr      = (unsigned short*)(ws + 67108864);     // (B,H,S,hd) bf16
  unsigned short* kr      = (unsigned short*)(ws + 100663296);    // (B,H,S,hd) bf16
  unsigned short* vt      = (unsigned short*)(ws + 134217728);    // (B,H,hd,S) bf16
  unsigned short* attnout = (unsigned short*)ws;                  // alias xb

  // 1) f32 -> bf16 conversion
  convert_kernel<<<16384, 256, 0, stream>>>(x, wq, wk, wv, wo, xb, wfused, wob);
  // 2) fused QKV GEMM (m97 128^2 + swizzle, XCD B-strips)
  gemm97<0><<<3072, 256, 0, stream>>>(xb, wfused, qr, kr, kout,
                                      vout, vt, nullptr, sp);
  // 3) causal flash attention (KVBLK=64, paired q-tiles)
  attn_kernel<<<dim3(16, 64), 256, 0, stream>>>(qr, kr, vt, attnout);
  // 4) output GEMM (m97 128^2 + swizzle)
  gemm97<1><<<1024, 256, 0, stream>>>(attnout, wob, nullptr, nullptr,
                                      nullptr, nullptr, nullptr, out, nullptr);
}

// Round 11
// 575.755 us; speedup vs baseline: 1.0311x; 1.0182x over previous
//
#include <hip/hip_runtime.h>
#include <hip/hip_bf16.h>

typedef __attribute__((ext_vector_type(4))) float f32x4;
typedef __attribute__((ext_vector_type(8))) short s16x8;

#define SEQ 2048
#define DM  2048
#define NH  16
#define HD  128

__device__ __forceinline__ unsigned short f2b(float f){
  unsigned int u = __builtin_bit_cast(unsigned int, f);
  u += 0x7fffu + ((u >> 16) & 1u);
  return (unsigned short)(u >> 16);
}
__device__ __forceinline__ float b2f(unsigned short h){
  unsigned int u = ((unsigned int)h) << 16;
  return __builtin_bit_cast(float, u);
}
__device__ __forceinline__ f32x4 mfma16(s16x8 a, s16x8 b, f32x4 c){
  return __builtin_amdgcn_mfma_f32_16x16x32_bf16(a, b, c, 0, 0, 0);
}

// ---------------------------------------------------------------------------
// One-shot f32 -> bf16 conversion: x -> xb, [wq|wk|wv] -> wfused, wo -> wob.
// ---------------------------------------------------------------------------
__global__ __launch_bounds__(256)
void convert_kernel(const float* __restrict__ x,  const float* __restrict__ wq,
                    const float* __restrict__ wk, const float* __restrict__ wv,
                    const float* __restrict__ wo,
                    unsigned short* __restrict__ xb,
                    unsigned short* __restrict__ wfused,
                    unsigned short* __restrict__ wob)
{
  size_t e = ((size_t)blockIdx.x * 256 + threadIdx.x) * 8;
  const float* src; unsigned short* dst;
  if (e < 16777216){ src = x + e; dst = xb + e; }
  else if (e < 29360128){
    size_t o = e - 16777216;
    int sel = (int)(o >> 22);
    const float* w = sel == 0 ? wq : (sel == 1 ? wk : wv);
    src = w + (o & 4194303); dst = wfused + o;
  } else {
    size_t o = e - 29360128;
    src = wo + o; dst = wob + o;
  }
  float4 a = ((const float4*)src)[0];
  float4 b = ((const float4*)src)[1];
  s16x8 v;
  v[0]=(short)f2b(a.x); v[1]=(short)f2b(a.y); v[2]=(short)f2b(a.z); v[3]=(short)f2b(a.w);
  v[4]=(short)f2b(b.x); v[5]=(short)f2b(b.y); v[6]=(short)f2b(b.z); v[7]=(short)f2b(b.w);
  *(s16x8*)dst = v;
}

// ---------------------------------------------------------------------------
// Ring-4 GEMM (R8 loop, fastest measured): 256x256 tile, BK=32, 8 waves,
// 4 x 32KB LDS slots, 3-deep prefetch, ONE s_barrier + vmcnt(8)/tile.
// NEW: MODE0 epilogue stages C through LDS (64x256 f32 chunks, pitch 260)
// and stores coalesced: RoPE rows as 32B bf16 + 64B f32 runs (8 threads =
// full 256B head-row), vt via LDS transpose (64B s-runs).
// L2 policy: XCD x owns fixed nb strip.
// ---------------------------------------------------------------------------
template<int MODE>
__global__ __launch_bounds__(512, 1)
void gemm8(const unsigned short* __restrict__ A,
           const unsigned short* __restrict__ B,
           unsigned short* __restrict__ qr, unsigned short* __restrict__ kr,
           float* __restrict__ koutf,
           float* __restrict__ voutf, unsigned short* __restrict__ vt,
           float* __restrict__ outf, const int* __restrict__ sp)
{
  extern __shared__ char lds[];
  const int tid  = threadIdx.x;
  const int lane = tid & 63;
  const int w    = tid >> 6;           // 0..7
  const int wr   = w >> 2;             // 0..1  (M half)
  const int wc   = w & 3;              // 0..3  (N quarter)
  const int l15  = lane & 15;
  const int lhi  = lane >> 4;          // 0..3
  const int rq   = lhi << 2;

  // XCD-resident B-strips: MODE0 nb = 3x + j%3, MODE1 nb = x.
  int bid = blockIdx.x;
  int x8 = bid & 7, jb = bid >> 3;
  int mb, nb;
  if (MODE == 0){ nb = 3*x8 + (jb % 3); mb = jb / 3; }
  else          { nb = x8;              mb = jb; }
  const int m0 = mb * 256, n0 = nb * 256;

  const int sp0 = (MODE == 0) ? sp[0] : 0;

  const unsigned short* Abase = A + (size_t)m0 * 2048;
  const unsigned short* Bbase = B + (size_t)n0 * 2048;

  f32x4 accL[4][4] = {};   // M-frags 0-3
  f32x4 accH[4][4] = {};   // M-frags 4-7

  auto STAGE = [&](const unsigned short* gbase, int slotoff, int t){
    #pragma unroll
    for (int r2 = 0; r2 < 2; r2++){
      int p  = r2*8192 + w*1024 + (lane << 4);     // physical LDS offset
      int lo = p ^ (((p >> 7) & 3) << 4);          // logical (involution)
      int row = lo >> 6, colB = lo & 63;
      __builtin_amdgcn_global_load_lds(
        (const __attribute__((address_space(1))) void*)
          (gbase + (size_t)row*2048 + t*32 + (colB >> 1)),
        (__attribute__((address_space(3))) void*)(lds + slotoff + r2*8192 + w*1024),
        16, 0, 0);
    }
  };
  auto LDA = [&](const char* base, int i0, s16x8* dst){
    #pragma unroll
    for (int i = 0; i < 4; i++){
      int row = wr*128 + (i0 + i)*16 + l15;
      int off = row*64 + lhi*16;
      dst[i] = *(const s16x8*)(base + (off ^ (((row >> 1) & 3) << 4)));
    }
  };
  auto LDB = [&](const char* base, s16x8* dst){
    #pragma unroll
    for (int j2 = 0; j2 < 4; j2++){
      int row = wc*64 + j2*16 + l15;
      int off = row*64 + lhi*16;
      dst[j2] = *(const s16x8*)(base + (off ^ (((row >> 1) & 3) << 4)));
    }
  };
  auto MM = [&](s16x8* a, s16x8* b, f32x4 (&ac)[4][4]){
    __builtin_amdgcn_s_setprio(1);
    #pragma unroll
    for (int i = 0; i < 4; i++)
      #pragma unroll
      for (int j2 = 0; j2 < 4; j2++)
        ac[i][j2] = mfma16(a[i], b[j2], ac[i][j2]);
    __builtin_amdgcn_s_setprio(0);
  };

#define TILE(T, ISSUE, VMW) { \
    const int s_ = (T) & 3; \
    const char* base_ = lds + s_*32768; \
    if (ISSUE){ \
      int so_ = (((T)+3) & 3)*32768; \
      STAGE(Abase, so_, (T)+3); \
      STAGE(Bbase, so_+16384, (T)+3); \
    } \
    s16x8 bfr[4], afL[4], afH[4]; \
    LDB(base_+16384, bfr); LDA(base_, 0, afL); LDA(base_, 4, afH); \
    MM(afL, bfr, accL); MM(afH, bfr, accH); \
    asm volatile("s_waitcnt vmcnt(" #VMW ")" ::: "memory"); \
    __builtin_amdgcn_s_barrier(); }

  // ---- prologue: stage tiles 0,1,2; wait tile 0 ----
  STAGE(Abase, 0, 0);      STAGE(Bbase, 16384, 0);
  STAGE(Abase, 32768, 1);  STAGE(Bbase, 49152, 1);
  STAGE(Abase, 65536, 2);  STAGE(Bbase, 81920, 2);
  asm volatile("s_waitcnt vmcnt(8)" ::: "memory");
  __builtin_amdgcn_s_barrier();

  for (int t = 0; t < 61; t++) TILE(t, 1, 8);
  TILE(61, 0, 4);
  TILE(62, 0, 0);
  { // t = 63: last tile, no wait/barrier
    const char* base_ = lds + 3*32768;
    s16x8 bfr[4], afL[4], afH[4];
    LDB(base_+16384, bfr); LDA(base_, 0, afL); LDA(base_, 4, afH);
    MM(afL, bfr, accL); MM(afH, bfr, accH);
  }
#undef TILE

  // ======================= epilogues =======================
  if (MODE == 1){
    #pragma unroll
    for (int h2 = 0; h2 < 2; h2++){
      f32x4 (&ac)[4][4] = h2 ? accH : accL;
      int ibase = h2 * 4;
      #pragma unroll
      for (int i = 0; i < 4; i++)
        #pragma unroll
        for (int r = 0; r < 4; r++){
          int m = m0 + wr*128 + (ibase+i)*16 + rq + r;
          #pragma unroll
          for (int j2 = 0; j2 < 4; j2++)
            outf[(size_t)m*DM + n0 + wc*64 + j2*16 + l15] = ac[i][j2][r];
        }
    }
    return;
  }

  const int b  = m0 >> 11;
  const int s0 = m0 & 2047;
  const int P  = 260;                      // LDS f32 pitch (1040B, 16B-aligned)
  float*  LF = (float*)lds;                // 64 x 260 f32 = 66.5KB
  float2* T2 = (float2*)(lds + 81920);     // [32 s_lo][128 f]
  float2* T1 = (float2*)(lds + 114688);    // [ 8 s_hi][128 f]

  __syncthreads();                         // K-loop LDS dead; reuse

  if (nb < 16){
    // ---- RoPE Q/K: chunked LDS staging + coalesced stores ----
    const bool isK = (nb >= 8);
    unsigned short* dqk = isK ? kr : qr;
    const int hq = nb & 7;
    // build angle tables (angle addition: pos = (sp0+s0+32*sh) + sl)
    for (int idx = tid; idx < 5120; idx += 512){
      int fl = idx & 127;
      float th = exp2f(-(float)(hq*128 + fl) * (13.287712379549449f / 1024.0f));
      float sn, cn;
      if (idx < 4096){
        __sincosf((float)(idx >> 7) * th, &sn, &cn);
        T2[idx] = make_float2(cn, sn);
      } else {
        int sh = (idx - 4096) >> 7;
        __sincosf((float)(sp0 + s0 + sh*32) * th, &sn, &cn);
        T1[idx - 4096] = make_float2(cn, sn);
      }
    }
    __syncthreads();

    const int row_l = tid >> 3;            // 0..63
    const int tr    = tid & 7;             // 0..7  (16 fl each)
    #pragma unroll 1
    for (int ck = 0; ck < 4; ck++){
      if (wr == (ck >> 1)){
        f32x4 (&ac)[4][4] = (ck & 1) ? accH : accL;
        #pragma unroll
        for (int i = 0; i < 4; i++)
          #pragma unroll
          for (int j2 = 0; j2 < 4; j2++)
            #pragma unroll
            for (int r = 0; r < 4; r++)
              LF[(i*16 + rq + r)*P + wc*64 + j2*16 + l15] = ac[i][j2][r];
      }
      __syncthreads();

      int s_local = ck*64 + row_l;
      int s  = s0 + s_local;
      int sh = s_local >> 5, sl = s_local & 31;
      const float* rowp = LF + row_l*P + tr*32;
      s16x8 qa0, qa1, qb0, qb1;
      f32x4 k0[4], k1[4];
      #pragma unroll
      for (int q = 0; q < 8; q++){
        f32x4 vv = *(const f32x4*)(rowp + q*4);
        #pragma unroll
        for (int e = 0; e < 2; e++){
          int f16 = 2*q + e;
          int fl  = tr*16 + f16;
          float x1 = vv[2*e], x2 = vv[2*e+1];
          float2 a1 = T1[sh*128 + fl];
          float2 a2 = T2[sl*128 + fl];
          float cn = a1.x*a2.x - a1.y*a2.y;
          float sn = a1.y*a2.x + a1.x*a2.y;
          float o0 = x1*cn - x2*sn;
          float o1 = x1*sn + x2*cn;
          if (f16 < 8){ qa0[f16] = (short)f2b(o0); qb0[f16] = (short)f2b(o1); }
          else        { qa1[f16-8] = (short)f2b(o0); qb1[f16-8] = (short)f2b(o1); }
          k0[f16>>2][f16&3] = o0;
          k1[f16>>2][f16&3] = o1;
        }
      }
      size_t a0 = ((size_t)(b*NH + hq    )*SEQ + s)*HD + tr*16;
      size_t a1 = ((size_t)(b*NH + hq + 8)*SEQ + s)*HD + tr*16;
      *(s16x8*)(dqk + a0)     = qa0;
      *(s16x8*)(dqk + a0 + 8) = qa1;
      *(s16x8*)(dqk + a1)     = qb0;
      *(s16x8*)(dqk + a1 + 8) = qb1;
      if (isK){
        #pragma unroll
        for (int q4 = 0; q4 < 4; q4++){
          *(f32x4*)(koutf + a0 + q4*4) = k0[q4];
          *(f32x4*)(koutf + a1 + q4*4) = k1[q4];
        }
      }
      __syncthreads();
    }
  } else {
    // ---- V: chunked LDS staging; vout rows + vt transpose, coalesced ----
    const int row_l = tid >> 3;
    const int tr    = tid & 7;
    const int dd2   = tid & 255;           // for vt phase
    const int sh2   = tid >> 8;            // 0..1
    #pragma unroll 1
    for (int ck = 0; ck < 4; ck++){
      if (wr == (ck >> 1)){
        f32x4 (&ac)[4][4] = (ck & 1) ? accH : accL;
        #pragma unroll
        for (int i = 0; i < 4; i++)
          #pragma unroll
          for (int j2 = 0; j2 < 4; j2++)
            #pragma unroll
            for (int r = 0; r < 4; r++)
              LF[(i*16 + rq + r)*P + wc*64 + j2*16 + l15] = ac[i][j2][r];
      }
      __syncthreads();

      // vout: row-major, 128B contiguous per thread
      {
        int s = s0 + ck*64 + row_l;
        int dg = (nb - 16)*256 + tr*32;
        int h = dg >> 7, dd = dg & 127;
        const float* rowp = LF + row_l*P + tr*32;
        float* vb = voutf + ((size_t)(b*NH + h)*SEQ + s)*HD + dd;
        #pragma unroll
        for (int q4 = 0; q4 < 8; q4++)
          *(f32x4*)(vb + q4*4) = *(const f32x4*)(rowp + q4*4);
      }
      // vt: transpose, 64B contiguous s-run per thread
      {
        int dg = (nb - 16)*256 + dd2;
        int h = dg >> 7, dd = dg & 127;
        int sb = s0 + ck*64 + sh2*32;
        s16x8 t0, t1, t2, t3;
        #pragma unroll
        for (int q = 0; q < 8; q++){
          t0[q] = (short)f2b(LF[(sh2*32 +      q)*P + dd2]);
          t1[q] = (short)f2b(LF[(sh2*32 +  8 + q)*P + dd2]);
          t2[q] = (short)f2b(LF[(sh2*32 + 16 + q)*P + dd2]);
          t3[q] = (short)f2b(LF[(sh2*32 + 24 + q)*P + dd2]);
        }
        unsigned short* vp = vt + ((size_t)(b*NH + h)*HD + dd)*SEQ + sb;
        *(s16x8*)(vp)      = t0;
        *(s16x8*)(vp + 8)  = t1;
        *(s16x8*)(vp + 16) = t2;
        *(s16x8*)(vp + 24) = t3;
      }
      __syncthreads();
    }
  }
}

// ---------------------------------------------------------------------------
// Causal flash attention v4 (unchanged, R10): 4 waves x 16 q-rows, KVBLK=64,
// paired q-tiles; K 64x256B XOR-swz; V^T/P 144B pitch; ones-MFMA rowsum;
// defer-max (THR=8).
// ---------------------------------------------------------------------------
__global__ __launch_bounds__(256)
void attn_kernel(const unsigned short* __restrict__ qr,
                 const unsigned short* __restrict__ kr,
                 const unsigned short* __restrict__ vt,
                 unsigned short* __restrict__ attnout)
{
  const int pair = blockIdx.x;          // 0..15
  const int bh   = blockIdx.y;          // 0..63
  const int tid  = threadIdx.x;
  const int lane = tid & 63;
  const int w    = tid >> 6;

  __shared__ __align__(16) char Klds[64 * 256];    // 16KB
  __shared__ __align__(16) char Vlds[128 * 144];   // 18KB
  __shared__ __align__(16) char Plds[4][16 * 144]; // 9KB

  const int l15 = lane & 15;
  const int lhi = lane >> 4;
  const int rq  = lhi << 2;
  char* pw = &Plds[w][0];

  s16x8 ones;
  #pragma unroll
  for (int i = 0; i < 8; i++) ones[i] = (short)0x3F80;

  const int b = bh >> 4, h = bh & 15;

  for (int ph = 0; ph < 2; ph++){
    const int qtile = ph ? (31 - pair) : pair;
    const int q0w = qtile*64 + w*16;

    s16x8 qf[4];
    const unsigned short* qbase = qr + ((size_t)bh*SEQ + q0w + l15) * HD + lhi*8;
    #pragma unroll
    for (int c = 0; c < 4; c++) qf[c] = *(const s16x8*)(qbase + c*32);

    f32x4 o[8] = {};
    f32x4 osum = {};
    float mrow[4] = {-1e30f,-1e30f,-1e30f,-1e30f};

    const int ntiles = qtile + 1;
    for (int t = 0; t < ntiles; t++){
      const int kv0 = t * 64;
      __syncthreads();
      { // stage K tile (64 x 128 bf16, rows 256B, XOR swz (r&15)<<4)
        int r = tid >> 2, q4 = tid & 3;
        const unsigned short* src = kr + ((size_t)bh*SEQ + kv0 + r) * HD + q4*32;
        int sw = (r & 15) << 4;
        char* drow = Klds + r*256;
        #pragma unroll
        for (int k = 0; k < 4; k++)
          *(s16x8*)(drow + ((q4*64 + k*16) ^ sw)) = *(const s16x8*)(src + k*8);
      }
      { // stage V^T tile (128 d-rows x 64 kv, 144B pitch)
        int r = tid >> 1, h2 = tid & 1;
        const unsigned short* src = vt + ((size_t)bh*HD + r) * SEQ + kv0 + h2*32;
        char* drow = Vlds + r*144 + h2*64;
        #pragma unroll
        for (int k = 0; k < 4; k++)
          *(s16x8*)(drow + k*16) = *(const s16x8*)(src + k*8);
      }
      __syncthreads();

      // ---- S = Q K^T (16 q x 64 kv as four 16x16 tiles) ----
      f32x4 st[4];
      #pragma unroll
      for (int j = 0; j < 4; j++) st[j] = (f32x4){0.f,0.f,0.f,0.f};
      #pragma unroll
      for (int j = 0; j < 4; j++){
        int krw = j*16 + l15;
        int sw  = (krw & 15) << 4;
        #pragma unroll
        for (int c = 0; c < 4; c++){
          s16x8 kf = *(const s16x8*)(Klds + krw*256 + ((c*64 + lhi*16) ^ sw));
          st[j] = mfma16(qf[c], kf, st[j]);
        }
      }

      const float sc = 0.08838834764831845f;
      #pragma unroll
      for (int j = 0; j < 4; j++)
        #pragma unroll
        for (int r = 0; r < 4; r++){
          int qrow = q0w + rq + r;
          int kvc  = kv0 + j*16 + l15;
          st[j][r] = (kvc > qrow) ? -1e30f : st[j][r] * sc;
        }

      float mt[4];
      #pragma unroll
      for (int r = 0; r < 4; r++)
        mt[r] = fmaxf(fmaxf(st[0][r], st[1][r]), fmaxf(st[2][r], st[3][r]));
      #pragma unroll
      for (int mk = 1; mk < 16; mk <<= 1)
        #pragma unroll
        for (int r = 0; r < 4; r++) mt[r] = fmaxf(mt[r], __shfl_xor(mt[r], mk));

      int ok = 1;
      #pragma unroll
      for (int r = 0; r < 4; r++) ok &= (mt[r] <= mrow[r] + 8.0f) ? 1 : 0;
      if (!__all(ok)){
        float al[4];
        #pragma unroll
        for (int r = 0; r < 4; r++){
          float mn = fmaxf(mrow[r], mt[r]);
          al[r] = __expf(mrow[r] - mn);
          mrow[r] = mn;
        }
        #pragma unroll
        for (int c = 0; c < 8; c++)
          #pragma unroll
          for (int r = 0; r < 4; r++) o[c][r] *= al[r];
        #pragma unroll
        for (int r = 0; r < 4; r++) osum[r] *= al[r];
      }

      // ---- P = exp(S - m) -> per-wave LDS (144B pitch) ----
      #pragma unroll
      for (int r = 0; r < 4; r++){
        char* prb = pw + (rq + r)*144;
        #pragma unroll
        for (int j = 0; j < 4; j++){
          float p = __expf(st[j][r] - mrow[r]);
          *(unsigned short*)(prb + (j*16 + l15)*2) = f2b(p);
        }
      }

      asm volatile("s_waitcnt lgkmcnt(0)" ::: "memory");

      // ---- O += P V (two K=32 passes) ----
      #pragma unroll
      for (int ks = 0; ks < 2; ks++){
        s16x8 pa = *(const s16x8*)(pw + l15*144 + ks*64 + lhi*16);
        #pragma unroll
        for (int c = 0; c < 8; c++){
          int d = c*16 + l15;
          s16x8 vf = *(const s16x8*)(Vlds + d*144 + ks*64 + lhi*16);
          o[c] = mfma16(pa, vf, o[c]);
        }
        osum = mfma16(pa, ones, osum);
      }
    }

    #pragma unroll
    for (int r = 0; r < 4; r++){
      float inv = 1.0f / osum[r];
      int s2 = q0w + rq + r;
      size_t base = ((size_t)(b*SEQ + s2)) * DM + h*HD;
      #pragma unroll
      for (int c = 0; c < 8; c++)
        attnout[base + c*16 + l15] = f2b(o[c][r] * inv);
    }
  }
}

// ---------------------------------------------------------------------------
extern "C" void kernel_launch(void* const* d_in, const int* in_sizes, int n_in,
                              void* d_out, int out_size, void* d_ws, size_t ws_size,
                              hipStream_t stream)
{
  const float* x  = (const float*)d_in[0];
  const float* wq = (const float*)d_in[1];
  const float* wk = (const float*)d_in[2];
  const float* wv = (const float*)d_in[3];
  const float* wo = (const float*)d_in[4];
  const int*   sp = (const int*)d_in[5];

  float* out  = (float*)d_out;            // (B,S,D) f32
  float* kout = out + 16777216;           // (B,H,S,hd) f32
  float* vout = out + 33554432;           // (B,H,S,hd) f32

  char* ws = (char*)d_ws;
  unsigned short* xb      = (unsigned short*)ws;                  // 8192x2048 bf16
  unsigned short* wfused  = (unsigned short*)(ws + 33554432);     // 6144x2048 bf16
  unsigned short* wob     = (unsigned short*)(ws + 58720256);     // 2048x2048 bf16
  unsigned short* qr      = (unsigned short*)(ws + 67108864);     // (B,H,S,hd) bf16
  unsigned short* kr      = (unsigned short*)(ws + 100663296);    // (B,H,S,hd) bf16
  unsigned short* vt      = (unsigned short*)(ws + 134217728);    // (B,H,hd,S) bf16
  unsigned short* attnout = (unsigned short*)ws;                  // alias xb

  hipFuncSetAttribute((const void*)gemm8<0>,
                      hipFuncAttributeMaxDynamicSharedMemorySize, 131072);
  hipFuncSetAttribute((const void*)gemm8<1>,
                      hipFuncAttributeMaxDynamicSharedMemorySize, 131072);

  // 1) f32 -> bf16 conversion
  convert_kernel<<<16384, 256, 0, stream>>>(x, wq, wk, wv, wo, xb, wfused, wob);
  // 2) fused QKV GEMM (ring-4 + coalesced chunked epilogue)
  gemm8<0><<<768, 512, 131072, stream>>>(xb, wfused, qr, kr, kout,
                                         vout, vt, nullptr, sp);
  // 3) causal flash attention (KVBLK=64, paired q-tiles)
  attn_kernel<<<dim3(16, 64), 256, 0, stream>>>(qr, kr, vt, attnout);
  // 4) output GEMM (ring-4)
  gemm8<1><<<256, 512, 131072, stream>>>(attnout, wob, nullptr, nullptr,
                                         nullptr, nullptr, nullptr, out, nullptr);
}